// Round 16
// baseline (120.910 us; speedup 1.0000x reference)
//
#include <hip/hip_runtime.h>
#include <math.h>

constexpr int H = 512, W = 512;
constexpr int N_ANGLES = 360;
constexpr int N_DET = 736;
constexpr int N_STEPS = 725;                 // ceil(hypot(512,512))
constexpr int SINO_SIZE = N_ANGLES * N_DET;  // 264960

constexpr int DET_TILE = 64;
constexpr int K_TILE   = 64;
constexpr int PITCH    = 100;  // dword cells; mult of 4 (16B chunks); need <= 97
constexpr int ROWS     = 93;
constexpr int QCHUNKS  = PITCH / 4;          // 25 16B-chunks/row (DMA path)
constexpr int MAXJ     = 5;                  // ceil(93*25/512)
// LDS: 93*100*4 = 37200 B; single buffer (r14: dbuf halved occupancy, -20%)

// padded f16-pair image (in d_ws): cell (y,x) = pack(v[y-PADY][x-PADX],
// v[y-PADY+1][x-PADX]) with v = zero-bordered x+reco.
constexpr int PADX = 96, PADY = 96;
constexpr int PW = 720;   // x0 in [-92,512] -> cols 4..707 < 720
constexpr int PH = 704;   // y0 in [-92,512] -> rows 4..700 < 704
constexpr size_t PAD_BYTES = (size_t)PW * PH * 4;

typedef float v2f __attribute__((ext_vector_type(2)));
typedef __fp16 h2f __attribute__((ext_vector_type(2)));
union PackU { unsigned u; h2f h; };

// ---------------------------------------------------------------------------
// Kernel 1a (DMA path): build f16 vertical-pair padded image + updated output.
// ---------------------------------------------------------------------------
__global__ void pad_kernel(const float* __restrict__ x,
                           const float* __restrict__ reco,
                           unsigned* __restrict__ padded2,
                           float* __restrict__ updated) {
    int i = blockIdx.x * blockDim.x + threadIdx.x;
    if (i >= PW * PH) return;
    int p = i / PW, q = i - p * PW;
    int gy = p - PADY, gx = q - PADX;
    float v0 = 0.0f, v1 = 0.0f;
    if ((unsigned)gx < (unsigned)W) {
        if ((unsigned)gy < (unsigned)H) {
            int gi = gy * W + gx;
            v0 = x[gi] + reco[gi];
            updated[gi] = v0;
        }
        if ((unsigned)(gy + 1) < (unsigned)H) {
            int gi = (gy + 1) * W + gx;
            v1 = x[gi] + reco[gi];
        }
    }
    PackU pk;
    pk.h = __builtin_amdgcn_cvt_pkrtz(v0, v1);
    padded2[i] = pk.u;
}

// ---------------------------------------------------------------------------
// Kernel 1b (fallback): updated = x + reco
// ---------------------------------------------------------------------------
__global__ void add_kernel(const float4* __restrict__ x,
                           const float4* __restrict__ reco,
                           float4* __restrict__ out) {
    int i = blockIdx.x * blockDim.x + threadIdx.x;
    float4 a = x[i];
    float4 b = reco[i];
    out[i] = make_float4(a.x + b.x, a.y + b.y, a.z + b.z, a.w + b.w);
}

// ---------------------------------------------------------------------------
// Kernel 2: forward projection (r13 structure + batch-8 sample pipeline).
// Block = (angle, 64 detectors), 512 threads; wave footprint 16 det x 4 k.
// Full k-tiles (the common case) give every lane EXACTLY 8 samples ->
// fast path: compute 8 addrs, issue 8 ds_read2_b32 (8 outstanding; the
// r12-r15 plateau was the serial per-lane LDS latency chain), then 8 lerps
// with 2 independent accumulators. Partial tiles use the generic loop.
// Cells are f16 vertical pairs: one ds_read2_b32 per bilinear sample.
// ---------------------------------------------------------------------------
template <bool DMA>
__global__ __launch_bounds__(512, 6) void radon_kernel(const void* __restrict__ imgv,
                                                       const float* __restrict__ angles,
                                                       float* __restrict__ sino) {
    __shared__ unsigned tile[ROWS * PITCH];

    const int tid = threadIdx.x;
    const int w   = tid >> 6;
    const int l   = tid & 63;
    const int dt_ = 16 * (w & 3) + (l & 15);   // detector within tile
    const int klr = 4 * (w >> 2) + (l >> 4);   // k residue 0..7
    const int a   = blockIdx.y;
    const int d0  = blockIdx.x * DET_TILE;

    const float theta = angles[a];
    const float c = cosf(theta);
    const float s = sinf(theta);
    const float ac = fabsf(c), as = fabsf(s);
    const float cx = (W - 1) * 0.5f;            // 255.5
    const float cy = (H - 1) * 0.5f;            // 255.5
    const float t_off = (N_STEPS - 1) * 0.5f;   // 362

    const float u   = (float)(d0 + dt_) - (N_DET - 1) * 0.5f;
    const float bxu = cx - s * u;               // px = c*t + bxu
    const float byu = cy + c * u;               // py = s*t + byu

    // ---- conservative block k-window via interval arithmetic over u ----
    const float uLo = (float)d0 - (N_DET - 1) * 0.5f;
    const float uHi = uLo + (DET_TILE - 1);
    float su0 = s * uLo, su1 = s * uHi;
    float smin = fminf(su0, su1), smax = fmaxf(su0, su1);
    float cu0 = c * uLo, cu1 = c * uHi;
    float cmin = fminf(cu0, cu1), cmax = fmaxf(cu0, cu1);

    float tmin = -1e30f, tmax = 1e30f;
    {   // exists u: px in (-1, W)  <=>  c*t in (xlo, xhi)
        float xlo = -1.0f - cx + smin;
        float xhi = (float)W - cx + smax;
        if (ac > 1e-12f) {
            float t0 = xlo / c, t1 = xhi / c;
            tmin = fmaxf(tmin, fminf(t0, t1));
            tmax = fminf(tmax, fmaxf(t0, t1));
        } else if (xlo > 0.0f || xhi < 0.0f) {
            tmax = -2e30f;
        }
    }
    {   // exists u: py in (-1, H)  <=>  s*t in (ylo, yhi)
        float ylo = -1.0f - cy - cmax;
        float yhi = (float)H - cy - cmin;
        if (as > 1e-12f) {
            float t0 = ylo / s, t1 = yhi / s;
            tmin = fmaxf(tmin, fminf(t0, t1));
            tmax = fminf(tmax, fmaxf(t0, t1));
        } else if (ylo > 0.0f || yhi < 0.0f) {
            tmax = -2e30f;
        }
    }
    const int kminU = (int)fminf(725.0f, fmaxf(0.0f, ceilf(tmin + t_off) - 1.0f));
    const int kmaxU = (int)fmaxf(-1.0f, fminf((float)(N_STEPS - 1), floorf(tmax + t_off) + 1.0f));

    const float ucf = uLo + 0.5f * (DET_TILE - 1);
    const float dx8 = 8.0f * c;
    const float dy8 = 8.0f * s;

    float acc = 0.0f;

    for (int k0 = kminU; k0 <= kmaxU; k0 += K_TILE) {
        const int k1 = min(k0 + K_TILE - 1, kmaxU);
        // ---- bbox of ALL sample positions for (u in tile, t in [t0,t1]) ----
        const float t0f = (float)k0 - t_off;
        const float dt  = (float)(k1 - k0);
        const float tc  = t0f + 0.5f * dt;
        const float xc_ = fmaf(c, tc, cx) - s * ucf;
        const float yc_ = fmaf(s, tc, cy) + c * ucf;
        const float hx = fmaf(0.5f * ac, dt, 0.5f * (DET_TILE - 1) * as) + 0.5f;
        const float hy = fmaf(0.5f * as, dt, 0.5f * (DET_TILE - 1) * ac) + 0.5f;
        const int x0 = ((int)floorf(xc_ - hx)) & ~3;     // 16B-chunk aligned
        const int y0 = (int)floorf(yc_ - hy);
        const int bh = min((int)floorf(yc_ + hy) + 1 - y0, ROWS);

        // ---- stage bh rows x PITCH cells ----
        if constexpr (DMA) {
            const unsigned* img2 = (const unsigned*)imgv;
            const int total = bh * QCHUNKS;
            const unsigned* srow = img2 + (size_t)(y0 + PADY) * PW + (x0 + PADX);
            #pragma unroll
            for (int j = 0; j < MAXJ; ++j) {
                const int i = tid + j * 512;
                if (i < total) {
                    const int r  = i / QCHUNKS;          // const-divisor magic mul
                    const int ch = i - r * QCHUNKS;
                    const unsigned* src = srow + r * PW + ch * 4;
                    unsigned* dst = tile + (size_t)(i & ~63) * 4;  // wave-uniform
                    __builtin_amdgcn_global_load_lds(
                        (const __attribute__((address_space(1))) unsigned*)src,
                        (__attribute__((address_space(3))) unsigned*)dst,
                        16, 0, 0);
                }
            }
        } else {
            const float* img = (const float*)imgv;
            const int total = bh * PITCH;
            for (int i = tid; i < total; i += 512) {
                int r  = i / PITCH;
                int gxx = i - r * PITCH + x0;
                int gy = y0 + r;
                float v0 = 0.0f, v1 = 0.0f;
                if ((unsigned)gxx < (unsigned)W) {
                    if ((unsigned)gy < (unsigned)H)       v0 = img[gy * W + gxx];
                    if ((unsigned)(gy + 1) < (unsigned)H) v1 = img[(gy + 1) * W + gxx];
                }
                PackU pk;
                pk.h = __builtin_amdgcn_cvt_pkrtz(v0, v1);
                tile[i] = pk.u;
            }
        }
        __syncthreads();   // drains vmcnt(0) before s_barrier

        // ---- sampling ----
        const int kst = k0 + klr;
        float px = fmaf(c, (float)kst - t_off, bxu) - (float)x0;
        float py = fmaf(s, (float)kst - t_off, byu) - (float)y0;

        if (k1 - k0 == K_TILE - 1) {
            // FAST PATH (uniform, 8 samples/lane): batch addrs -> batch reads
            // (8 outstanding ds_read2) -> batch lerps (2 accumulators).
            float wxv[8], wyv[8];
            unsigned q0v[8], q1v[8];
            #pragma unroll
            for (int i = 0; i < 8; ++i) {
                int xi = (int)px;                 // trunc == floor (>=0)
                int yi = (int)py;
                wxv[i] = __builtin_amdgcn_fractf(px);
                wyv[i] = __builtin_amdgcn_fractf(py);
                int idx = __mul24(yi, PITCH) + xi;
                q0v[i] = tile[idx];               // ds_read2_b32 (0,1)
                q1v[i] = tile[idx + 1];
                px += dx8;
                py += dy8;
            }
            float acc0 = 0.0f, acc1 = 0.0f;
            #pragma unroll
            for (int i = 0; i < 8; ++i) {
                PackU q0, q1;
                q0.u = q0v[i];
                q1.u = q1v[i];
                v2f c0 = {(float)q0.h.x, (float)q0.h.y};   // (v00, v10)
                v2f c1 = {(float)q1.h.x, (float)q1.h.y};   // (v01, v11)
                v2f diff = c1 - c0;
                v2f wx2 = {wxv[i], wxv[i]};
                v2f tb = __builtin_elementwise_fma(wx2, diff, c0);
                if (i & 1) acc1 = fmaf(wyv[i], tb.y - tb.x, acc1 + tb.x);
                else       acc0 = fmaf(wyv[i], tb.y - tb.x, acc0 + tb.x);
            }
            acc += acc0 + acc1;
        } else {
            // generic tail path (partial k-tile)
            for (int k = kst; k <= k1; k += 8) {
                int xi = (int)px;
                int yi = (int)py;
                float wx = __builtin_amdgcn_fractf(px);
                float wy = __builtin_amdgcn_fractf(py);
                int idx = __mul24(yi, PITCH) + xi;
                PackU q0, q1;
                q0.u = tile[idx];
                q1.u = tile[idx + 1];
                v2f c0 = {(float)q0.h.x, (float)q0.h.y};
                v2f c1 = {(float)q1.h.x, (float)q1.h.y};
                v2f diff = c1 - c0;
                v2f wx2 = {wx, wx};
                v2f tb = __builtin_elementwise_fma(wx2, diff, c0);
                acc = fmaf(wy, tb.y - tb.x, acc + tb.x);
                px += dx8;
                py += dy8;
            }
        }
        __syncthreads();
    }

    // ---- reduce 8 k-residues per detector ----
    acc += __shfl_xor(acc, 16);
    acc += __shfl_xor(acc, 32);
    float* scratch = (float*)tile;
    if (l < 16) scratch[w * 16 + l] = acc;
    __syncthreads();
    if (tid < DET_TILE) {
        int g  = tid >> 4;
        int dd = tid & 15;
        float r = scratch[g * 16 + dd] + scratch[(g + 4) * 16 + dd];
        int dglob = d0 + tid;
        if (dglob < N_DET) sino[a * N_DET + dglob] = r;   // dets 736..767 phantom
    }
}

// ---------------------------------------------------------------------------
extern "C" void kernel_launch(void* const* d_in, const int* in_sizes, int n_in,
                              void* d_out, int out_size, void* d_ws, size_t ws_size,
                              hipStream_t stream) {
    const float* x      = (const float*)d_in[0];
    const float* reco   = (const float*)d_in[1];
    const float* angles = (const float*)d_in[2];

    float* sino    = (float*)d_out;              // (360, 736)
    float* updated = (float*)d_out + SINO_SIZE;  // (512, 512)

    dim3 grid((N_DET + DET_TILE - 1) / DET_TILE, N_ANGLES);   // (12, 360)

    if (ws_size >= PAD_BYTES) {
        unsigned* padded2 = (unsigned*)d_ws;
        pad_kernel<<<(PW * PH + 255) / 256, 256, 0, stream>>>(x, reco, padded2, updated);
        radon_kernel<true><<<grid, 512, 0, stream>>>(padded2, angles, sino);
    } else {
        int n4 = (H * W) / 4;
        add_kernel<<<n4 / 256, 256, 0, stream>>>(
            (const float4*)x, (const float4*)reco, (float4*)updated);
        radon_kernel<false><<<grid, 512, 0, stream>>>(updated, angles, sino);
    }
}

// Round 18
// 101.980 us; speedup vs baseline: 1.1856x; 1.1856x over previous
//
#include <hip/hip_runtime.h>
#include <math.h>

constexpr int H = 512, W = 512;
constexpr int N_ANGLES = 360;
constexpr int N_DET = 736;
constexpr int N_STEPS = 725;                 // ceil(hypot(512,512))
constexpr int SINO_SIZE = N_ANGLES * N_DET;  // 264960

constexpr int DET_TILE = 64;
constexpr int ANG_TILE = 2;
constexpr int K_TILE   = 56;   // 4 k-residues/lane -> 14 samples/lane/phase
constexpr int PITCH    = 100;  // mult of 4 (16B DMA chunks); width need <= 96
constexpr int ROWS     = 94;   // height need <= 94 (|s|55+63|c|+1+6.1+3)
constexpr int QCHUNKS  = PITCH / 4;          // 25 16B-chunks/row
constexpr int MAXJ     = 5;                  // ceil(94*25/512)
// LDS: 94*100*4 = 37600 B -> 4 blocks/CU @ 512 thr

// padded f32 image (in d_ws): global (x,y) -> padded (x+PADX, y+PADY), zero border
constexpr int PADX = 96, PADY = 96;
constexpr int PW = 720;   // x0 in [-96, 524] -> cols 0..719
constexpr int PH = 704;   // y0 in [-96, 514] -> rows 0..703
constexpr size_t PAD_BYTES = (size_t)PW * PH * 4;

typedef float v2f __attribute__((ext_vector_type(2)));

// ---------------------------------------------------------------------------
// Kernel 1a (DMA path): padded = zero-bordered (x + reco); also writes updated.
// ---------------------------------------------------------------------------
__global__ void pad_kernel(const float* __restrict__ x,
                           const float* __restrict__ reco,
                           float* __restrict__ padded,
                           float* __restrict__ updated) {
    int i = blockIdx.x * blockDim.x + threadIdx.x;
    if (i >= PW * PH) return;
    int p = i / PW, q = i - p * PW;
    int gy = p - PADY, gx = q - PADX;
    float v = 0.0f;
    if ((unsigned)gy < (unsigned)H && (unsigned)gx < (unsigned)W) {
        int gi = gy * W + gx;
        v = x[gi] + reco[gi];
        updated[gi] = v;
    }
    padded[i] = v;
}

// ---------------------------------------------------------------------------
// Kernel 1b (fallback): updated = x + reco
// ---------------------------------------------------------------------------
__global__ void add_kernel(const float4* __restrict__ x,
                           const float4* __restrict__ reco,
                           float4* __restrict__ out) {
    int i = blockIdx.x * blockDim.x + threadIdx.x;
    float4 a = x[i];
    float4 b = reco[i];
    out[i] = make_float4(a.x + b.x, a.y + b.y, a.z + b.z, a.w + b.w);
}

// ---------------------------------------------------------------------------
// Kernel 2: forward projection; LDS tile SHARED ACROSS 2 ADJACENT ANGLES.
// Block = (angle pair, 64 dets), 512 threads.
// Lane map: det = 16*(w&3) + (l&15); angle al = (l>>4)&1; kr = (l>>5)+2*(w>>2).
// r17 crash fix: (1) empty window -> (kmn=N_STEPS, kmx=-1) sentinels so the
// union can never drag kminU to 0 (r17 faulted staging tiles ~200px off-image
// at k=0); (2) x0/y0 clamped to the padded image's addressable window (never
// binds per capacity proof; makes OOB staging structurally impossible).
// Bbox = union of the two angles' FULL tile parallelogram boxes -> every
// sampled position is staged; padded zeros give exact results.
// ---------------------------------------------------------------------------
template <bool DMA>
__global__ __launch_bounds__(512, 8) void radon_kernel(const float* __restrict__ img,
                                                       const float* __restrict__ angles,
                                                       float* __restrict__ sino) {
    __shared__ float tile[ROWS * PITCH];

    const int tid = threadIdx.x;
    const int w   = tid >> 6;
    const int l   = tid & 63;
    const int dt_ = 16 * (w & 3) + (l & 15);   // detector within tile
    const int al  = (l >> 4) & 1;              // angle within pair
    const int kr  = (l >> 5) + 2 * (w >> 2);   // k residue 0..3
    const int a0  = blockIdx.y * ANG_TILE;
    const int d0  = blockIdx.x * DET_TILE;

    const float th0 = angles[a0];
    const float th1 = angles[a0 + 1];
    const float c0a = cosf(th0), s0a = sinf(th0);
    const float c1a = cosf(th1), s1a = sinf(th1);
    const float cx = (W - 1) * 0.5f;            // 255.5
    const float cy = (H - 1) * 0.5f;            // 255.5
    const float t_off = (N_STEPS - 1) * 0.5f;   // 362

    const float c = al ? c1a : c0a;
    const float s = al ? s1a : s0a;

    const float u   = (float)(d0 + dt_) - (N_DET - 1) * 0.5f;
    const float bxu = cx - s * u;               // px = c*t + bxu
    const float byu = cy + c * u;               // py = s*t + byu

    const float uLo = (float)d0 - (N_DET - 1) * 0.5f;
    const float uHi = uLo + (DET_TILE - 1);
    const float ucf = uLo + 0.5f * (DET_TILE - 1);

    // ---- conservative window (exists u), per angle; EMPTY -> (725,-1) ----
    auto windowOf = [&](float ca, float sa, int& kmn, int& kmx) {
        float aca = fabsf(ca), asa = fabsf(sa);
        float su0 = sa * uLo, su1 = sa * uHi;
        float smn = fminf(su0, su1), smx = fmaxf(su0, su1);
        float cu0 = ca * uLo, cu1 = ca * uHi;
        float cmn = fminf(cu0, cu1), cmx = fmaxf(cu0, cu1);
        float tmin = -1e30f, tmax = 1e30f;
        {
            float xlo = -1.0f - cx + smn;
            float xhi = (float)W - cx + smx;
            if (aca > 1e-12f) {
                float t0 = xlo / ca, t1 = xhi / ca;
                tmin = fmaxf(tmin, fminf(t0, t1));
                tmax = fminf(tmax, fmaxf(t0, t1));
            } else if (xlo > 0.0f || xhi < 0.0f) {
                tmax = -2e30f;
            }
        }
        {
            float ylo = -1.0f - cy - cmx;
            float yhi = (float)H - cy - cmn;
            if (asa > 1e-12f) {
                float t0 = ylo / sa, t1 = yhi / sa;
                tmin = fmaxf(tmin, fminf(t0, t1));
                tmax = fminf(tmax, fmaxf(t0, t1));
            } else if (ylo > 0.0f || yhi < 0.0f) {
                tmax = -2e30f;
            }
        }
        kmn = (int)fminf(725.0f, fmaxf(0.0f, ceilf(tmin + t_off) - 1.0f));
        kmx = (int)fmaxf(-1.0f, fminf((float)(N_STEPS - 1), floorf(tmax + t_off) + 1.0f));
        if (kmn > kmx) { kmn = N_STEPS; kmx = -1; }   // SENTINEL: never expand union
    };

    int kmn0, kmx0, kmn1, kmx1;
    windowOf(c0a, s0a, kmn0, kmx0);
    windowOf(c1a, s1a, kmn1, kmx1);
    const int kminU = min(kmn0, kmn1);
    const int kmaxU = max(kmx0, kmx1);

    const v2f dinc = {4.0f * c, 4.0f * s};   // k step = 4 (4 residues)

    float acc = 0.0f;

    for (int k0 = kminU; k0 <= kmaxU; k0 += K_TILE) {
        const int k1 = min(k0 + K_TILE - 1, kmaxU);
        const float t0f = (float)k0 - t_off;
        const float dtf = (float)(k1 - k0);
        const float tc  = t0f + 0.5f * dtf;

        // ---- per-angle full-tile bbox, unioned ----
        float xmn =  1e30f, xmx = -1e30f, ymn = 1e30f, ymx = -1e30f;
        {
            float ca = c0a, sa = s0a;
            #pragma unroll
            for (int ai = 0; ai < 2; ++ai) {
                float aca = fabsf(ca), asa = fabsf(sa);
                float xc_ = fmaf(ca, tc, cx) - sa * ucf;
                float yc_ = fmaf(sa, tc, cy) + ca * ucf;
                float hx = fmaf(0.5f * aca, dtf, 0.5f * (DET_TILE - 1) * asa) + 0.5f;
                float hy = fmaf(0.5f * asa, dtf, 0.5f * (DET_TILE - 1) * aca) + 0.5f;
                xmn = fminf(xmn, xc_ - hx);
                xmx = fmaxf(xmx, xc_ + hx);
                ymn = fminf(ymn, yc_ - hy);
                ymx = fmaxf(ymx, yc_ + hy);
                ca = c1a; sa = s1a;
            }
        }
        int x0 = ((int)floorf(xmn)) & ~3;                // 16B-chunk aligned
        int y0 = (int)floorf(ymn);
        // clamp into addressable padded window (never binds per capacity proof)
        x0 = min(max(x0, -PADX), PW - PADX - PITCH);     // [-96, 524]
        y0 = min(max(y0, -PADY), PH - PADY - ROWS);      // [-96, 514]
        const int bh = min((int)floorf(ymx) + 2 - y0, ROWS);

        // ---- stage bh rows x PITCH cols ----
        if constexpr (DMA) {
            const int total = bh * QCHUNKS;
            const float* srow = img + (size_t)(y0 + PADY) * PW + (x0 + PADX);
            #pragma unroll
            for (int j = 0; j < MAXJ; ++j) {
                const int i = tid + j * 512;
                if (i < total) {
                    const int r  = i / QCHUNKS;          // const-divisor magic mul
                    const int ch = i - r * QCHUNKS;
                    const float* src = srow + r * PW + ch * 4;
                    float* dst = tile + (size_t)(i & ~63) * 4;  // wave-uniform
                    __builtin_amdgcn_global_load_lds(
                        (const __attribute__((address_space(1))) unsigned*)src,
                        (__attribute__((address_space(3))) unsigned*)dst,
                        16, 0, 0);
                }
            }
        } else {
            const int total = bh * PITCH;
            for (int i = tid; i < total; i += 512) {
                int r  = i / PITCH;
                int gxx = i - r * PITCH + x0;
                int gy = y0 + r;
                float v = 0.0f;
                if ((unsigned)gxx < (unsigned)W && (unsigned)gy < (unsigned)H)
                    v = img[gy * W + gxx];
                tile[i] = v;
            }
        }
        __syncthreads();   // drains vmcnt(0) before s_barrier

        // ---- branch-free sampling from LDS (packed-f32 lerp) ----
        const int kst = k0 + kr;
        v2f pos = {fmaf(c, (float)kst - t_off, bxu) - (float)x0,
                   fmaf(s, (float)kst - t_off, byu) - (float)y0};
        #pragma unroll 4
        for (int k = kst; k <= k1; k += 4) {
            int xi = (int)pos.x;                 // trunc == floor (>= 0)
            int yi = (int)pos.y;
            float wx = __builtin_amdgcn_fractf(pos.x);
            float wy = __builtin_amdgcn_fractf(pos.y);
            int idx = __mul24(yi, PITCH) + xi;
            v2f cc0 = {tile[idx],     tile[idx + PITCH]};      // ds_read2 (0,100)
            v2f cc1 = {tile[idx + 1], tile[idx + PITCH + 1]};  // ds_read2 (1,101)
            v2f diff = cc1 - cc0;
            v2f wx2 = {wx, wx};
            v2f tb = __builtin_elementwise_fma(wx2, diff, cc0);  // (top, bot)
            acc = fmaf(wy, tb.y - tb.x, acc + tb.x);
            pos += dinc;
        }
        __syncthreads();
    }

    // ---- reduce 4 k-residues per (angle, det) ----
    acc += __shfl_xor(acc, 32);                 // kr bit0 (l>>5)
    float* scratch = tile;                      // reads all behind barriers
    if (l < 32) scratch[w * 32 + l] = acc;      // 8 waves x 32 = 256 floats
    __syncthreads();
    if (tid < 128) {
        int g  = tid >> 5;                      // det group (w&3)
        int ll = tid & 31;                      // det-low (ll&15), angle bit (ll>>4)
        float r = scratch[g * 32 + ll] + scratch[(g + 4) * 32 + ll];  // kr bit1
        int d = d0 + 16 * g + (ll & 15);
        int ang = a0 + ((ll >> 4) & 1);
        if (d < N_DET) sino[ang * N_DET + d] = r;   // last block: dets 736..767 phantom
    }
}

// ---------------------------------------------------------------------------
extern "C" void kernel_launch(void* const* d_in, const int* in_sizes, int n_in,
                              void* d_out, int out_size, void* d_ws, size_t ws_size,
                              hipStream_t stream) {
    const float* x      = (const float*)d_in[0];
    const float* reco   = (const float*)d_in[1];
    const float* angles = (const float*)d_in[2];

    float* sino    = (float*)d_out;              // (360, 736)
    float* updated = (float*)d_out + SINO_SIZE;  // (512, 512)

    dim3 grid((N_DET + DET_TILE - 1) / DET_TILE, N_ANGLES / ANG_TILE);   // (12, 180)

    if (ws_size >= PAD_BYTES) {
        float* padded = (float*)d_ws;
        pad_kernel<<<(PW * PH + 255) / 256, 256, 0, stream>>>(x, reco, padded, updated);
        radon_kernel<true><<<grid, 512, 0, stream>>>(padded, angles, sino);
    } else {
        int n4 = (H * W) / 4;
        add_kernel<<<n4 / 256, 256, 0, stream>>>(
            (const float4*)x, (const float4*)reco, (float4*)updated);
        radon_kernel<false><<<grid, 512, 0, stream>>>(updated, angles, sino);
    }
}

// Round 19
// 101.054 us; speedup vs baseline: 1.1965x; 1.0092x over previous
//
#include <hip/hip_runtime.h>
#include <math.h>

constexpr int H = 512, W = 512;
constexpr int N_ANGLES = 360;
constexpr int N_DET = 736;
constexpr int N_STEPS = 725;                 // ceil(hypot(512,512))
constexpr int SINO_SIZE = N_ANGLES * N_DET;  // 264960

constexpr int THREADS  = 256;
constexpr int DET_TILE = 64;
constexpr int K_TILE   = 32;
constexpr int PITCH    = 84;   // mult of 4 (16B chunks); need <= 78; mod32=20 -> 2-way banks
constexpr int ROWS     = 75;   // need <= 75
constexpr int QCHUNKS  = PITCH / 4;          // 21 16B-chunks/row
constexpr int MAXJ     = 7;                  // ceil(75*21/256) = 7
// LDS: 75*84*4 = 25200 B -> 6 blocks/CU @ 256 thr = 24 waves/CU, 6 pipelines

// padded f32 image (in d_ws): global (x,y) -> padded (x+PADX, y+PADY), zeros
constexpr int PADX = 96, PADY = 96;
constexpr int PW = 720;   // x0 in [-96, 540] -> cols 0..719
constexpr int PH = 704;   // y0 in [-96, 533] -> rows 0..703
constexpr size_t PAD_BYTES = (size_t)PW * PH * 4;

typedef float v2f __attribute__((ext_vector_type(2)));

// ---------------------------------------------------------------------------
// Kernel 1a (DMA path): padded = zero-bordered (x + reco); also writes updated.
// ---------------------------------------------------------------------------
__global__ void pad_kernel(const float* __restrict__ x,
                           const float* __restrict__ reco,
                           float* __restrict__ padded,
                           float* __restrict__ updated) {
    int i = blockIdx.x * blockDim.x + threadIdx.x;
    if (i >= PW * PH) return;
    int p = i / PW, q = i - p * PW;
    int gy = p - PADY, gx = q - PADX;
    float v = 0.0f;
    if ((unsigned)gy < (unsigned)H && (unsigned)gx < (unsigned)W) {
        int gi = gy * W + gx;
        v = x[gi] + reco[gi];
        updated[gi] = v;
    }
    padded[i] = v;
}

// ---------------------------------------------------------------------------
// Kernel 1b (fallback): updated = x + reco
// ---------------------------------------------------------------------------
__global__ void add_kernel(const float4* __restrict__ x,
                           const float4* __restrict__ reco,
                           float4* __restrict__ out) {
    int i = blockIdx.x * blockDim.x + threadIdx.x;
    float4 a = x[i];
    float4 b = reco[i];
    out[i] = make_float4(a.x + b.x, a.y + b.y, a.z + b.z, a.w + b.w);
}

// ---------------------------------------------------------------------------
// Kernel 2: forward projection (r12 structure, 256-thread blocks, K_TILE=32).
// r18 postmortem: time tracks pipeline concurrency, not phase count/LDS
// traffic. 256-thread blocks halve the waves stalled per barrier and fit 6
// independent block pipelines/CU (vs 4) at 24 waves/CU.
// Wave map: w = tid>>6 owns dets 16w..16w+15; klr = l>>4 = k residue 0..3.
// Per-wave epilogue (no cross-wave reduction, no barrier).
// ---------------------------------------------------------------------------
template <bool DMA>
__global__ __launch_bounds__(THREADS, 6) void radon_kernel(const float* __restrict__ img,
                                                           const float* __restrict__ angles,
                                                           float* __restrict__ sino) {
    __shared__ float tile[ROWS * PITCH];

    const int tid = threadIdx.x;
    const int w   = tid >> 6;                  // wave 0..3 = det group
    const int l   = tid & 63;
    const int dt_ = 16 * w + (l & 15);         // detector within tile
    const int klr = l >> 4;                    // k residue 0..3
    const int a   = blockIdx.y;
    const int d0  = blockIdx.x * DET_TILE;

    const float theta = angles[a];
    const float c = cosf(theta);
    const float s = sinf(theta);
    const float ac = fabsf(c), as = fabsf(s);
    const float cx = (W - 1) * 0.5f;            // 255.5
    const float cy = (H - 1) * 0.5f;            // 255.5
    const float t_off = (N_STEPS - 1) * 0.5f;   // 362

    const float u   = (float)(d0 + dt_) - (N_DET - 1) * 0.5f;
    const float bxu = cx - s * u;               // px = c*t + bxu
    const float byu = cy + c * u;               // py = s*t + byu

    // ---- conservative block k-window via interval arithmetic over u ----
    const float uLo = (float)d0 - (N_DET - 1) * 0.5f;
    const float uHi = uLo + (DET_TILE - 1);
    float su0 = s * uLo, su1 = s * uHi;
    float smin = fminf(su0, su1), smax = fmaxf(su0, su1);
    float cu0 = c * uLo, cu1 = c * uHi;
    float cmin = fminf(cu0, cu1), cmax = fmaxf(cu0, cu1);

    float tmin = -1e30f, tmax = 1e30f;
    {   // exists u: px in (-1, W)  <=>  c*t in (xlo, xhi)
        float xlo = -1.0f - cx + smin;
        float xhi = (float)W - cx + smax;
        if (ac > 1e-12f) {
            float t0 = xlo / c, t1 = xhi / c;
            tmin = fmaxf(tmin, fminf(t0, t1));
            tmax = fminf(tmax, fmaxf(t0, t1));
        } else if (xlo > 0.0f || xhi < 0.0f) {
            tmax = -2e30f;
        }
    }
    {   // exists u: py in (-1, H)  <=>  s*t in (ylo, yhi)
        float ylo = -1.0f - cy - cmax;
        float yhi = (float)H - cy - cmin;
        if (as > 1e-12f) {
            float t0 = ylo / s, t1 = yhi / s;
            tmin = fmaxf(tmin, fminf(t0, t1));
            tmax = fminf(tmax, fmaxf(t0, t1));
        } else if (ylo > 0.0f || yhi < 0.0f) {
            tmax = -2e30f;
        }
    }
    int kminU = (int)fminf(725.0f, fmaxf(0.0f, ceilf(tmin + t_off) - 1.0f));
    int kmaxU = (int)fmaxf(-1.0f, fminf((float)(N_STEPS - 1), floorf(tmax + t_off) + 1.0f));
    if (kminU > kmaxU) { kminU = N_STEPS; kmaxU = -1; }   // empty: skip loop

    const float ucf = uLo + 0.5f * (DET_TILE - 1);
    const v2f dinc = {4.0f * c, 4.0f * s};      // k step = 4 residues

    float acc = 0.0f;

    for (int k0 = kminU; k0 <= kmaxU; k0 += K_TILE) {
        const int k1 = min(k0 + K_TILE - 1, kmaxU);
        // ---- bbox of ALL sample positions for (u in tile, t in [t0,t1]) ----
        const float t0f = (float)k0 - t_off;
        const float dt  = (float)(k1 - k0);
        const float tc  = t0f + 0.5f * dt;
        const float xc_ = fmaf(c, tc, cx) - s * ucf;
        const float yc_ = fmaf(s, tc, cy) + c * ucf;
        const float hx = fmaf(0.5f * ac, dt, 0.5f * (DET_TILE - 1) * as) + 0.5f;
        const float hy = fmaf(0.5f * as, dt, 0.5f * (DET_TILE - 1) * ac) + 0.5f;
        int x0 = ((int)floorf(xc_ - hx)) & ~3;           // 16B-chunk aligned
        int y0 = (int)floorf(yc_ - hy);
        // hard clamps into the padded image's addressable window (never bind
        // per capacity proof; make OOB staging structurally impossible)
        x0 = min(max(x0, -PADX), PW - PADX - PITCH);     // [-96, 540]
        y0 = min(max(y0, -PADY), PH - PADY - ROWS);      // [-96, 533]
        const int bh = min((int)floorf(yc_ + hy) + 2 - y0, ROWS);

        // ---- stage bh rows x PITCH cols ----
        if constexpr (DMA) {
            const int total = bh * QCHUNKS;
            const float* srow = img + (size_t)(y0 + PADY) * PW + (x0 + PADX);
            #pragma unroll
            for (int j = 0; j < MAXJ; ++j) {
                const int i = tid + j * THREADS;
                if (i < total) {
                    const int r  = i / QCHUNKS;          // const-divisor magic mul
                    const int ch = i - r * QCHUNKS;
                    const float* src = srow + r * PW + ch * 4;
                    float* dst = tile + (size_t)(i & ~63) * 4;  // wave-uniform
                    __builtin_amdgcn_global_load_lds(
                        (const __attribute__((address_space(1))) unsigned*)src,
                        (__attribute__((address_space(3))) unsigned*)dst,
                        16, 0, 0);
                }
            }
        } else {
            const int total = bh * PITCH;
            for (int i = tid; i < total; i += THREADS) {
                int r  = i / PITCH;
                int gxx = i - r * PITCH + x0;
                int gy = y0 + r;
                float v = 0.0f;
                if ((unsigned)gxx < (unsigned)W && (unsigned)gy < (unsigned)H)
                    v = img[gy * W + gxx];
                tile[i] = v;
            }
        }
        __syncthreads();   // drains vmcnt(0) before s_barrier

        // ---- branch-free sampling from LDS (packed-f32 lerp) ----
        // px,py >= 0 by bbox construction -> truncation == floor, fract valid
        const int kst = k0 + klr;
        v2f pos = {fmaf(c, (float)kst - t_off, bxu) - (float)x0,
                   fmaf(s, (float)kst - t_off, byu) - (float)y0};
        #pragma unroll 4
        for (int k = kst; k <= k1; k += 4) {
            int xi = (int)pos.x;
            int yi = (int)pos.y;
            float wx = __builtin_amdgcn_fractf(pos.x);
            float wy = __builtin_amdgcn_fractf(pos.y);
            int idx = __mul24(yi, PITCH) + xi;
            v2f c0 = {tile[idx],     tile[idx + PITCH]};      // ds_read2 (0,84)
            v2f c1 = {tile[idx + 1], tile[idx + PITCH + 1]};  // ds_read2 (1,85)
            v2f diff = c1 - c0;
            v2f wx2 = {wx, wx};
            v2f tb = __builtin_elementwise_fma(wx2, diff, c0);  // (top, bot)
            acc = fmaf(wy, tb.y - tb.x, acc + tb.x);
            pos += dinc;
        }
        __syncthreads();
    }

    // ---- per-wave reduction: k-residue lives in lane bits 4,5 ----
    acc += __shfl_xor(acc, 16);
    acc += __shfl_xor(acc, 32);
    if (l < 16) {
        int d = d0 + 16 * w + l;
        if (d < N_DET) sino[a * N_DET + d] = acc;   // last block: dets 736.. phantom
    }
}

// ---------------------------------------------------------------------------
extern "C" void kernel_launch(void* const* d_in, const int* in_sizes, int n_in,
                              void* d_out, int out_size, void* d_ws, size_t ws_size,
                              hipStream_t stream) {
    const float* x      = (const float*)d_in[0];
    const float* reco   = (const float*)d_in[1];
    const float* angles = (const float*)d_in[2];

    float* sino    = (float*)d_out;              // (360, 736)
    float* updated = (float*)d_out + SINO_SIZE;  // (512, 512)

    dim3 grid((N_DET + DET_TILE - 1) / DET_TILE, N_ANGLES);   // (12, 360)

    if (ws_size >= PAD_BYTES) {
        float* padded = (float*)d_ws;
        pad_kernel<<<(PW * PH + 255) / 256, 256, 0, stream>>>(x, reco, padded, updated);
        radon_kernel<true><<<grid, THREADS, 0, stream>>>(padded, angles, sino);
    } else {
        int n4 = (H * W) / 4;
        add_kernel<<<n4 / 256, 256, 0, stream>>>(
            (const float4*)x, (const float4*)reco, (float4*)updated);
        radon_kernel<false><<<grid, THREADS, 0, stream>>>(updated, angles, sino);
    }
}

// Round 20
// 98.643 us; speedup vs baseline: 1.2257x; 1.0244x over previous
//
#include <hip/hip_runtime.h>
#include <math.h>

constexpr int H = 512, W = 512;
constexpr int N_ANGLES = 360;
constexpr int N_DET = 736;
constexpr int N_STEPS = 725;                 // ceil(hypot(512,512))
constexpr int SINO_SIZE = N_ANGLES * N_DET;  // 264960

constexpr int THREADS   = 256;               // 4 waves/block
constexpr int WAVE_DETS = 16;                // dets per wave
constexpr int K_TILE    = 32;                // 4 k-residues x 8 samples/lane
constexpr int PITCH     = 44;   // dwords; mult of 4; need <= 42; mod32=12 -> 2-way banks
constexpr int ROWS      = 38;   // need <= 38 (sqrt(31^2+15^2)+3.6)
constexpr int QCHUNKS   = PITCH / 4;         // 11 16B-chunks/row
constexpr int TILE_DW   = ROWS * PITCH;      // 1672 dwords = 6688 B per wave
constexpr int MAXJ      = 7;                 // ceil(38*11/64) = 7 chunks/lane
// LDS: 4 waves x 6688 = 26752 B/block -> 6 blocks/CU = 24 independent wave
// pipelines (r12-r19 ledger: block-wide barrier serialized each block into
// ONE pipeline; this kernel has NO barrier in the k-loop).

// padded f32 image (in d_ws): global (x,y) -> padded (x+PADX, y+PADY), zeros
constexpr int PADX = 96, PADY = 96;
constexpr int PW = 720;   // x0 in [-96, 580] -> cols 0..719
constexpr int PH = 704;   // y0 in [-96, 570] -> rows 0..703
constexpr size_t PAD_BYTES = (size_t)PW * PH * 4;

typedef float v2f __attribute__((ext_vector_type(2)));

// ---------------------------------------------------------------------------
// Kernel 1a (DMA path): padded = zero-bordered (x + reco); also writes updated.
// ---------------------------------------------------------------------------
__global__ void pad_kernel(const float* __restrict__ x,
                           const float* __restrict__ reco,
                           float* __restrict__ padded,
                           float* __restrict__ updated) {
    int i = blockIdx.x * blockDim.x + threadIdx.x;
    if (i >= PW * PH) return;
    int p = i / PW, q = i - p * PW;
    int gy = p - PADY, gx = q - PADX;
    float v = 0.0f;
    if ((unsigned)gy < (unsigned)H && (unsigned)gx < (unsigned)W) {
        int gi = gy * W + gx;
        v = x[gi] + reco[gi];
        updated[gi] = v;
    }
    padded[i] = v;
}

// ---------------------------------------------------------------------------
// Kernel 1b (fallback): updated = x + reco
// ---------------------------------------------------------------------------
__global__ void add_kernel(const float4* __restrict__ x,
                           const float4* __restrict__ reco,
                           float4* __restrict__ out) {
    int i = blockIdx.x * blockDim.x + threadIdx.x;
    float4 a = x[i];
    float4 b = reco[i];
    out[i] = make_float4(a.x + b.x, a.y + b.y, a.z + b.z, a.w + b.w);
}

// ---------------------------------------------------------------------------
// Kernel 2: forward projection, WAVE-PRIVATE tiles, zero barriers in k-loop.
// Each wave: 16 dets x full k-range; per 32-k phase it stages its own
// 44x38 tile (7 global_load_lds) -> s_waitcnt vmcnt(0) (per-wave, not a
// block barrier) -> 8 samples/lane. Waves are fully independent -> 24
// pipelines/CU instead of the 4-6 barrier-coupled block pipelines of r12-r19.
// Lane map: dt_ = l&15 (det), klr = l>>4 (k residue 0..3).
// ---------------------------------------------------------------------------
template <bool DMA>
__global__ __launch_bounds__(THREADS, 6) void radon_kernel(const float* __restrict__ img,
                                                           const float* __restrict__ angles,
                                                           float* __restrict__ sino) {
    __shared__ float tiles[4][TILE_DW];

    const int tid = threadIdx.x;
    const int w   = tid >> 6;
    const int l   = tid & 63;
    float* tile = tiles[w];

    const int dt_ = l & 15;                    // detector within wave group
    const int klr = l >> 4;                    // k residue 0..3
    const int a   = blockIdx.y;
    const int d0w = blockIdx.x * 64 + w * WAVE_DETS;   // wave's first det

    const float theta = angles[a];
    const float c = cosf(theta);
    const float s = sinf(theta);
    const float ac = fabsf(c), as = fabsf(s);
    const float cx = (W - 1) * 0.5f;            // 255.5
    const float cy = (H - 1) * 0.5f;            // 255.5
    const float t_off = (N_STEPS - 1) * 0.5f;   // 362

    const float u   = (float)(d0w + dt_) - (N_DET - 1) * 0.5f;
    const float bxu = cx - s * u;               // px = c*t + bxu
    const float byu = cy + c * u;               // py = s*t + byu

    // ---- conservative per-wave k-window via interval arithmetic over u ----
    const float uLo = (float)d0w - (N_DET - 1) * 0.5f;
    const float uHi = uLo + (WAVE_DETS - 1);
    float su0 = s * uLo, su1 = s * uHi;
    float smin = fminf(su0, su1), smax = fmaxf(su0, su1);
    float cu0 = c * uLo, cu1 = c * uHi;
    float cmin = fminf(cu0, cu1), cmax = fmaxf(cu0, cu1);

    float tmin = -1e30f, tmax = 1e30f;
    {   // exists u: px in (-1, W)  <=>  c*t in (xlo, xhi)
        float xlo = -1.0f - cx + smin;
        float xhi = (float)W - cx + smax;
        if (ac > 1e-12f) {
            float t0 = xlo / c, t1 = xhi / c;
            tmin = fmaxf(tmin, fminf(t0, t1));
            tmax = fminf(tmax, fmaxf(t0, t1));
        } else if (xlo > 0.0f || xhi < 0.0f) {
            tmax = -2e30f;
        }
    }
    {   // exists u: py in (-1, H)  <=>  s*t in (ylo, yhi)
        float ylo = -1.0f - cy - cmax;
        float yhi = (float)H - cy - cmin;
        if (as > 1e-12f) {
            float t0 = ylo / s, t1 = yhi / s;
            tmin = fmaxf(tmin, fminf(t0, t1));
            tmax = fminf(tmax, fmaxf(t0, t1));
        } else if (ylo > 0.0f || yhi < 0.0f) {
            tmax = -2e30f;
        }
    }
    int kminU = (int)fminf(725.0f, fmaxf(0.0f, ceilf(tmin + t_off) - 1.0f));
    int kmaxU = (int)fmaxf(-1.0f, fminf((float)(N_STEPS - 1), floorf(tmax + t_off) + 1.0f));
    if (kminU > kmaxU) { kminU = N_STEPS; kmaxU = -1; }   // empty: skip loop

    const float ucf = uLo + 0.5f * (WAVE_DETS - 1);
    const v2f dinc = {4.0f * c, 4.0f * s};      // k step = 4 residues

    float acc = 0.0f;

    for (int k0 = kminU; k0 <= kmaxU; k0 += K_TILE) {
        const int k1 = min(k0 + K_TILE - 1, kmaxU);
        // ---- bbox of wave's sample positions (u in 16-det span, t span) ----
        const float t0f = (float)k0 - t_off;
        const float dt  = (float)(k1 - k0);
        const float tc  = t0f + 0.5f * dt;
        const float xc_ = fmaf(c, tc, cx) - s * ucf;
        const float yc_ = fmaf(s, tc, cy) + c * ucf;
        const float hx = fmaf(0.5f * ac, dt, 0.5f * (WAVE_DETS - 1) * as) + 0.5f;
        const float hy = fmaf(0.5f * as, dt, 0.5f * (WAVE_DETS - 1) * ac) + 0.5f;
        int x0 = ((int)floorf(xc_ - hx)) & ~3;           // 16B-chunk aligned
        int y0 = (int)floorf(yc_ - hy);
        // hard clamps into padded addressable window (never bind for real waves)
        x0 = min(max(x0, -PADX), PW - PADX - PITCH);
        y0 = min(max(y0, -PADY), PH - PADY - ROWS);
        const int bh = min((int)floorf(yc_ + hy) + 2 - y0, ROWS);

        // ---- stage bh rows x PITCH cols into the WAVE'S tile ----
        if constexpr (DMA) {
            const int total = bh * QCHUNKS;
            const float* srow = img + (size_t)(y0 + PADY) * PW + (x0 + PADX);
            #pragma unroll
            for (int j = 0; j < MAXJ; ++j) {
                const int i = l + j * 64;
                if (i < total) {
                    const int r  = i / QCHUNKS;          // const-divisor magic mul
                    const int ch = i - r * QCHUNKS;
                    const float* src = srow + r * PW + ch * 4;
                    float* dst = tile + (size_t)(j * 64) * 4;   // wave-uniform
                    __builtin_amdgcn_global_load_lds(
                        (const __attribute__((address_space(1))) unsigned*)src,
                        (__attribute__((address_space(3))) unsigned*)dst,
                        16, 0, 0);
                }
            }
            // per-wave wait for own DMA; "memory" keeps ds_reads below
            asm volatile("s_waitcnt vmcnt(0)" ::: "memory");
        } else {
            const int total = bh * PITCH;
            for (int i = l; i < total; i += 64) {
                int r  = i / PITCH;
                int gxx = i - r * PITCH + x0;
                int gy = y0 + r;
                float v = 0.0f;
                if ((unsigned)gxx < (unsigned)W && (unsigned)gy < (unsigned)H)
                    v = img[gy * W + gxx];
                tile[i] = v;
            }
            // same-wave ds_write -> ds_read ordering is program order; the
            // compiler's lgkmcnt waits cover it. No barrier needed.
        }

        // ---- branch-free sampling from the wave's tile ----
        // px,py >= 0 by bbox construction -> truncation == floor, fract valid
        const int kst = k0 + klr;
        v2f pos = {fmaf(c, (float)kst - t_off, bxu) - (float)x0,
                   fmaf(s, (float)kst - t_off, byu) - (float)y0};
        #pragma unroll 4
        for (int k = kst; k <= k1; k += 4) {
            int xi = (int)pos.x;
            int yi = (int)pos.y;
            float wx = __builtin_amdgcn_fractf(pos.x);
            float wy = __builtin_amdgcn_fractf(pos.y);
            int idx = __mul24(yi, PITCH) + xi;
            v2f c0 = {tile[idx],     tile[idx + PITCH]};      // ds_read2 (0,44)
            v2f c1 = {tile[idx + 1], tile[idx + PITCH + 1]};  // ds_read2 (1,45)
            v2f diff = c1 - c0;
            v2f wx2 = {wx, wx};
            v2f tb = __builtin_elementwise_fma(wx2, diff, c0);  // (top, bot)
            acc = fmaf(wy, tb.y - tb.x, acc + tb.x);
            pos += dinc;
        }
        // no barrier: next phase's DMA only issues after reads retired
        // (their results feed acc before the loop back-edge).
    }

    // ---- per-wave reduction: k-residue lives in lane bits 4,5 ----
    acc += __shfl_xor(acc, 16);
    acc += __shfl_xor(acc, 32);
    if (l < WAVE_DETS) {
        int d = d0w + l;
        if (d < N_DET) sino[a * N_DET + d] = acc;   // last block: waves 2,3 phantom
    }
}

// ---------------------------------------------------------------------------
extern "C" void kernel_launch(void* const* d_in, const int* in_sizes, int n_in,
                              void* d_out, int out_size, void* d_ws, size_t ws_size,
                              hipStream_t stream) {
    const float* x      = (const float*)d_in[0];
    const float* reco   = (const float*)d_in[1];
    const float* angles = (const float*)d_in[2];

    float* sino    = (float*)d_out;              // (360, 736)
    float* updated = (float*)d_out + SINO_SIZE;  // (512, 512)

    dim3 grid((N_DET + 63) / 64, N_ANGLES);      // (12, 360)

    if (ws_size >= PAD_BYTES) {
        float* padded = (float*)d_ws;
        pad_kernel<<<(PW * PH + 255) / 256, 256, 0, stream>>>(x, reco, padded, updated);
        radon_kernel<true><<<grid, THREADS, 0, stream>>>(padded, angles, sino);
    } else {
        int n4 = (H * W) / 4;
        add_kernel<<<n4 / 256, 256, 0, stream>>>(
            (const float4*)x, (const float4*)reco, (float4*)updated);
        radon_kernel<false><<<grid, THREADS, 0, stream>>>(updated, angles, sino);
    }
}